// Round 1
// baseline (285.781 us; speedup 1.0000x reference)
//
#include <hip/hip_runtime.h>

typedef _Float16 f16;
typedef _Float16 f16x8 __attribute__((ext_vector_type(8)));
typedef _Float16 f16x4 __attribute__((ext_vector_type(4)));
typedef float    f32x4 __attribute__((ext_vector_type(4)));
typedef unsigned int u32t;

#define AS1 __attribute__((address_space(1)))
#define AS3 __attribute__((address_space(3)))

static __device__ __forceinline__ void gload_lds16(const void* g, void* l) {
  __builtin_amdgcn_global_load_lds((const AS1 u32t*)g, (AS3 u32t*)l, 16, 0, 0);
}

static __device__ __forceinline__ f16x8 zero8() {
  f16x8 z;
#pragma unroll
  for (int j = 0; j < 8; ++j) z[j] = (f16)0;
  return z;
}

// ---------------- convert x (fp32 -> fp16) ----------------
__global__ void k_cvt_x(const float* __restrict__ in, f16* __restrict__ out, int n4) {
  int stride = gridDim.x * blockDim.x;
  for (int i = blockIdx.x * blockDim.x + threadIdx.x; i < n4; i += stride) {
    float4 v = ((const float4*)in)[i];
    f16x4 o;
    o[0] = (f16)v.x; o[1] = (f16)v.y; o[2] = (f16)v.z; o[3] = (f16)v.w;
    ((f16x4*)out)[i] = o;
  }
}

// ---------------- convert + transpose W: [1280][N] f32 -> [N][1280] f16 ----------------
__global__ void k_cvt_w_t(const float* __restrict__ W, f16* __restrict__ Wt, int N) {
  __shared__ float T[32][33];
  int bk = blockIdx.x % 40;          // 1280/32
  int bn = blockIdx.x / 40;
  int k0 = bk * 32, n0 = bn * 32;
  int r = threadIdx.x >> 5;          // 0..7
  int c = threadIdx.x & 31;
#pragma unroll
  for (int i = 0; i < 4; ++i)
    T[r + i * 8][c] = W[(size_t)(k0 + r + i * 8) * N + n0 + c];
  __syncthreads();
#pragma unroll
  for (int i = 0; i < 4; ++i)
    Wt[(size_t)(n0 + r + i * 8) * 1280 + k0 + c] = (f16)T[c][r + i * 8];
}

// ---------------- NT GEMM: C[M,NCOLS] = A[M,1280] * Bt[NCOLS,1280]^T + bias ----------------
template<int NCOLS, bool F16OUT>
__global__ __launch_bounds__(256, 2)
void gemm_nt(const f16* __restrict__ A, const f16* __restrict__ Bt,
             const float* __restrict__ bias, void* __restrict__ Cout)
{
  __shared__ __align__(16) f16 sA[128 * 64];
  __shared__ __align__(16) f16 sB[128 * 64];
  const int tid = threadIdx.x;
  const int wave = tid >> 6, lane = tid & 63;
  constexpr int NBN = NCOLS / 128;
  const int bm = blockIdx.x / NBN, bn = blockIdx.x % NBN;
  const long row0 = (long)bm * 128, col0 = (long)bn * 128;

  f32x4 acc[4][4];
#pragma unroll
  for (int i = 0; i < 4; ++i)
#pragma unroll
    for (int j = 0; j < 4; ++j) acc[i][j] = (f32x4){0.f, 0.f, 0.f, 0.f};

  const int wr = (wave >> 1) * 64, wc = (wave & 1) * 64;

  // staging geometry: per wave 4 segments of 1KB per tile.
  // LDS linear o = seg*1024 + lane*16 ; tile row r = o>>7 ; col-byte cb = o&127.
  // physical LDS is linear; global SOURCE column is pre-swizzled: scb = cb ^ ((r&7)<<4)
  int segr[4], segoff[4];
#pragma unroll
  for (int i = 0; i < 4; ++i) {
    int o = (wave * 4 + i) * 1024 + lane * 16;
    int r = o >> 7, cb = o & 127;
    segr[i] = r;
    segoff[i] = cb ^ ((r & 7) << 4);
  }

  const char* Ab = (const char*)A;
  const char* Bb = (const char*)Bt;

  for (int kt = 0; kt < 20; ++kt) {
    __syncthreads();   // previous compute done before overwrite
#pragma unroll
    for (int i = 0; i < 4; ++i) {
      const char* ga = Ab + ((row0 + segr[i]) * 1280 + kt * 64) * 2 + segoff[i];
      gload_lds16(ga, (char*)sA + (wave * 4 + i) * 1024);
      const char* gb = Bb + ((col0 + segr[i]) * 1280 + kt * 64) * 2 + segoff[i];
      gload_lds16(gb, (char*)sB + (wave * 4 + i) * 1024);
    }
    __syncthreads();   // compiler drains vmcnt before barrier

#pragma unroll
    for (int kk = 0; kk < 2; ++kk) {
      const int rl = lane & 15, g = lane >> 4, x7 = lane & 7;
      const int ph = (kk * 4 + g) ^ x7;
      f16x8 af[4], bf[4];
#pragma unroll
      for (int mt = 0; mt < 4; ++mt)
        af[mt] = *(const f16x8*)(sA + (wr + mt * 16 + rl) * 64 + ph * 8);
#pragma unroll
      for (int nt = 0; nt < 4; ++nt)
        bf[nt] = *(const f16x8*)(sB + (wc + nt * 16 + rl) * 64 + ph * 8);
#pragma unroll
      for (int mt = 0; mt < 4; ++mt)
#pragma unroll
        for (int nt = 0; nt < 4; ++nt)
          acc[mt][nt] = __builtin_amdgcn_mfma_f32_16x16x32_f16(af[mt], bf[nt], acc[mt][nt], 0, 0, 0);
    }
  }

  const int rl = lane & 15, g = lane >> 4;
#pragma unroll
  for (int mt = 0; mt < 4; ++mt) {
#pragma unroll
    for (int nt = 0; nt < 4; ++nt) {
      long c = col0 + wc + nt * 16 + rl;
      float bv = bias[c];
#pragma unroll
      for (int r = 0; r < 4; ++r) {
        long rr = row0 + wr + mt * 16 + g * 4 + r;
        float v = acc[mt][nt][r] + bv;
        if (F16OUT) ((f16*)Cout)[rr * NCOLS + c] = (f16)v;
        else        ((float*)Cout)[rr * NCOLS + c] = v;
      }
    }
  }
}

// ---------------- V transpose: qkv v-part -> vt[b*16+h][80][2048] ----------------
__global__ void k_vt(const f16* __restrict__ qkv, f16* __restrict__ vt) {
  __shared__ __align__(16) f16 T[128 * 136];
  int bid = blockIdx.x;              // 64 bh * 16 s-chunks
  int sc16 = bid & 15, bh = bid >> 4;
  int b = bh >> 4, h = bh & 15;
  int s0 = sc16 * 128;
  int t = threadIdx.x;
#pragma unroll
  for (int i = 0; i < 5; ++i) {
    int cid = i * 256 + t;           // 1280 = 128 s * 10 chunks
    int s = cid / 10, c = cid % 10;
    const f16* g = qkv + (size_t)((s0 + s) * 4 + b) * 3840 + 2560 + h * 80 + c * 8;
    f16x8 v = *(const f16x8*)g;
    int phys = c ^ ((s >> 3) & 7);
    *(f16x8*)(T + s * 136 + phys * 8) = v;
  }
  __syncthreads();
#pragma unroll
  for (int i = 0; i < 5; ++i) {
    int oid = i * 256 + t;           // 1280 = 80 hd * 16 s-subchunks
    int sc8 = oid & 15, hd = oid >> 4;
    f16x8 o;
#pragma unroll
    for (int j = 0; j < 8; ++j) {
      int row = sc8 * 8 + j;
      int phys = (hd >> 3) ^ (sc8 & 7);
      o[j] = T[row * 136 + phys * 8 + (hd & 7)];
    }
    *(f16x8*)(vt + (size_t)(bh * 80 + hd) * 2048 + s0 + sc8 * 8) = o;
  }
}

// ---------------- windowed attention ----------------
// block: (b, h, seg, qc) ; 512 threads = 8 waves * 16 queries
__global__ __launch_bounds__(512, 2)
void k_attn(const f16* __restrict__ qkv, const f16* __restrict__ vt,
            f16* __restrict__ ctx)
{
  __shared__ __align__(16) f16 sK[256 * 104];   // keys x (80 + zero-pad to 96, stride 104)
  __shared__ __align__(16) f16 sV[80 * 264];    // hd x 256 keys (stride 264)
  __shared__ __align__(16) f16 sP[128 * 72];    // q x 64-key chunk (stride 72)

  const int bid = blockIdx.x;                   // 1024
  const int qc = bid & 1, seg = (bid >> 1) & 7, h = (bid >> 4) & 15, b = bid >> 8;
  const int t = threadIdx.x;
  const int wave = t >> 6, lane = t & 63;
  const int s_key0 = seg * 256;

  // stage K (k-part of qkv, col base 1280 + h*80)
#pragma unroll
  for (int i = 0; i < 5; ++i) {
    int cid = i * 512 + t;                      // 2560 = 256 keys * 10 chunks
    int key = cid / 10, c = cid % 10;
    const f16* g = qkv + (size_t)((s_key0 + key) * 4 + b) * 3840 + 1280 + h * 80 + c * 8;
    *(f16x8*)(sK + key * 104 + c * 8) = *(const f16x8*)g;
  }
  { // zero cols 80..95
    int key = t >> 1, c = t & 1;
    *(f16x8*)(sK + key * 104 + 80 + c * 8) = zero8();
  }
  // stage V from vt
#pragma unroll
  for (int i = 0; i < 5; ++i) {
    int cid = i * 512 + t;                      // 2560 = 80 hd * 32 chunks
    int hd = cid >> 5, c = cid & 31;
    const f16* g = vt + (size_t)((b * 16 + h) * 80 + hd) * 2048 + s_key0 + c * 8;
    *(f16x8*)(sV + hd * 264 + c * 8) = *(const f16x8*)g;
  }

  // Q fragments direct from global (col base h*80); wave owns 16 queries
  const int q0 = s_key0 + qc * 128 + wave * 16;
  const int rl = lane & 15, g = lane >> 4;
  f16x8 qf[3];
  {
    const f16* gq = qkv + (size_t)((q0 + rl) * 4 + b) * 3840 + h * 80;
    qf[0] = *(const f16x8*)(gq + g * 8);
    qf[1] = *(const f16x8*)(gq + 32 + g * 8);
    if (g < 2) qf[2] = *(const f16x8*)(gq + 64 + g * 8);
    else       qf[2] = zero8();
  }
  __syncthreads();

  // QK^T : sc[nt] covers keys nt*16+(lane&15), rows g*4+r
  f32x4 sc[16];
#pragma unroll
  for (int nt = 0; nt < 16; ++nt) sc[nt] = (f32x4){0.f, 0.f, 0.f, 0.f};
#pragma unroll
  for (int nt = 0; nt < 16; ++nt) {
#pragma unroll
    for (int kk = 0; kk < 3; ++kk) {
      f16x8 bf = *(const f16x8*)(sK + (nt * 16 + rl) * 104 + kk * 32 + g * 8);
      sc[nt] = __builtin_amdgcn_mfma_f32_16x16x32_f16(qf[kk], bf, sc[nt], 0, 0, 0);
    }
  }

  // softmax (exact, full 256-key window in regs)
  const float scale = 0.11180339887498949f;
  float inv[4];
#pragma unroll
  for (int r = 0; r < 4; ++r) {
    float m = -1e30f;
#pragma unroll
    for (int nt = 0; nt < 16; ++nt) m = fmaxf(m, sc[nt][r]);
#pragma unroll
    for (int off = 8; off >= 1; off >>= 1) m = fmaxf(m, __shfl_xor(m, off));
    m *= scale;
    float sum = 0.f;
#pragma unroll
    for (int nt = 0; nt < 16; ++nt) {
      float p = __expf(sc[nt][r] * scale - m);
      sc[nt][r] = p;
      sum += p;
    }
#pragma unroll
    for (int off = 8; off >= 1; off >>= 1) sum += __shfl_xor(sum, off);
    inv[r] = 1.0f / sum;
  }

  // PV in 4 chunks of 64 keys; P bounced through wave-private sP rows
  f32x4 o[5];
#pragma unroll
  for (int nt = 0; nt < 5; ++nt) o[nt] = (f32x4){0.f, 0.f, 0.f, 0.f};
  const int prow0 = wave * 16;
  for (int ch = 0; ch < 4; ++ch) {
    __syncthreads();
#pragma unroll
    for (int f = 0; f < 4; ++f) {
      int nt = ch * 4 + f;
#pragma unroll
      for (int r = 0; r < 4; ++r)
        sP[(prow0 + g * 4 + r) * 72 + f * 16 + rl] = (f16)sc[nt][r];
    }
    __syncthreads();
#pragma unroll
    for (int kk = 0; kk < 2; ++kk) {
      f16x8 pa = *(const f16x8*)(sP + (prow0 + rl) * 72 + kk * 32 + g * 8);
#pragma unroll
      for (int nt = 0; nt < 5; ++nt) {
        f16x8 vb = *(const f16x8*)(sV + (nt * 16 + rl) * 264 + ch * 64 + kk * 32 + g * 8);
        o[nt] = __builtin_amdgcn_mfma_f32_16x16x32_f16(pa, vb, o[nt], 0, 0, 0);
      }
    }
  }

  // epilogue: normalize, store ctx fp16
#pragma unroll
  for (int nt = 0; nt < 5; ++nt) {
    int hd = nt * 16 + rl;
#pragma unroll
    for (int r = 0; r < 4; ++r) {
      long qrow = q0 + g * 4 + r;
      float v = o[nt][r] * inv[r];
      ctx[(qrow * 4 + b) * 1280 + h * 80 + hd] = (f16)v;
    }
  }
}

extern "C" void kernel_launch(void* const* d_in, const int* in_sizes, int n_in,
                              void* d_out, int out_size, void* d_ws, size_t ws_size,
                              hipStream_t stream)
{
  const float* x     = (const float*)d_in[0];
  const float* Wqkv  = (const float*)d_in[1];
  const float* bqkv  = (const float*)d_in[2];
  const float* Wproj = (const float*)d_in[3];
  const float* bproj = (const float*)d_in[4];

  char* ws = (char*)d_ws;
  f16* X16   = (f16*)(ws);                 // 20,971,520 B (reused as CTX16 after gemm1)
  f16* WQT   = (f16*)(ws + 20971520);      //  9,830,400 B
  f16* WPT   = (f16*)(ws + 30801920);      // 13,107,200 B
  f16* QKV16 = (f16*)(ws + 43909120);      // 62,914,560 B
  f16* VT    = (f16*)(ws + 106823680);     // 20,971,520 B  (total 127,795,200 B)
  f16* CTX16 = X16;                        // x dead after gemm1

  k_cvt_x<<<4096, 256, 0, stream>>>(x, X16, 8192 * 1280 / 4);
  k_cvt_w_t<<<40 * 120, 256, 0, stream>>>(Wqkv, WQT, 3840);
  k_cvt_w_t<<<40 * 160, 256, 0, stream>>>(Wproj, WPT, 5120);
  gemm_nt<3840, true ><<<64 * 30, 256, 0, stream>>>(X16, WQT, bqkv, QKV16);
  k_vt<<<1024, 256, 0, stream>>>(QKV16, VT);
  k_attn<<<1024, 512, 0, stream>>>(QKV16, VT, CTX16);
  gemm_nt<5120, false><<<64 * 40, 256, 0, stream>>>(CTX16, WPT, bproj, d_out);
}